// Round 1
// baseline (4554.231 us; speedup 1.0000x reference)
//
#include <hip/hip_runtime.h>
#include <hip/hip_bf16.h>

#define NN   100000
#define NE   800000
#define DIN  512
#define DHID 512
#define DOUT 256

__device__ __forceinline__ float bf2f(unsigned short b) {
    union { unsigned u; float f; } c; c.u = ((unsigned)b) << 16; return c.f;
}
__device__ __forceinline__ unsigned short f2bf(float f) {
    union { float f; unsigned u; } c; c.f = f;
    unsigned u = c.u;
    u += 0x7FFFu + ((u >> 16) & 1u);   // round-to-nearest-even
    return (unsigned short)(u >> 16);
}

// ---------- degree / dinv ----------
__global__ void k_init_deg(float* deg) {
    int i = blockIdx.x * 256 + threadIdx.x;
    if (i < NN) deg[i] = 1.0f;                 // self-loop
}
__global__ void k_count_deg(const int* __restrict__ dst, float* __restrict__ deg) {
    int i = blockIdx.x * 256 + threadIdx.x;
    if (i < NE) atomicAdd(&deg[dst[i]], 1.0f);
}
__global__ void k_dinv(float* deg) {
    int i = blockIdx.x * 256 + threadIdx.x;
    if (i < NN) deg[i] = rsqrtf(deg[i]);       // deg >= 1 always
}

// ---------- fp32 register-tiled GEMM, epilogue writes bf16 H + self-loop init ----------
__device__ __forceinline__ void loadA4(const float* p, float* o) {
    const float4 v = *reinterpret_cast<const float4*>(p);
    o[0] = v.x; o[1] = v.y; o[2] = v.z; o[3] = v.w;
}
__device__ __forceinline__ void loadA4(const unsigned short* p, float* o) {
    const ushort4 v = *reinterpret_cast<const ushort4*>(p);
    o[0] = bf2f(v.x); o[1] = bf2f(v.y); o[2] = bf2f(v.z); o[3] = bf2f(v.w);
}

template<typename TA>
__global__ __launch_bounds__(256) void k_gemm(
    const TA* __restrict__ A, const float* __restrict__ W,
    const float* __restrict__ dinv,
    unsigned short* __restrict__ Hb,   // [M,Nc] bf16 raw h (for gather)
    float* __restrict__ Agg,           // [M,Nc] f32, init = h * dinv^2 (self-loop)
    int M, int K, int Nc)
{
    const int BM = 128, BN = 128, BK = 8;
    __shared__ float As[BK][BM + 4];
    __shared__ float Ws[BK][BN + 4];
    const int bm = blockIdx.x * BM;
    const int bn = blockIdx.y * BN;
    const int t  = threadIdx.x;
    const int tx = t & 15, ty = t >> 4;

    float acc[8][8];
    #pragma unroll
    for (int i = 0; i < 8; ++i)
        #pragma unroll
        for (int j = 0; j < 8; ++j) acc[i][j] = 0.f;

    const int arow = t >> 1;
    const int acol = (t & 1) * 4;
    const int wrow = t >> 5;
    const int wcol = (t & 31) * 4;

    for (int k0 = 0; k0 < K; k0 += BK) {
        float av[4] = {0.f, 0.f, 0.f, 0.f};
        const int gm = bm + arow;
        if (gm < M) loadA4(A + (size_t)gm * K + k0 + acol, av);
        As[acol + 0][arow] = av[0];
        As[acol + 1][arow] = av[1];
        As[acol + 2][arow] = av[2];
        As[acol + 3][arow] = av[3];
        const float4 wv = *reinterpret_cast<const float4*>(
            W + (size_t)(k0 + wrow) * Nc + bn + wcol);
        *reinterpret_cast<float4*>(&Ws[wrow][wcol]) = wv;
        __syncthreads();
        #pragma unroll
        for (int kk = 0; kk < BK; ++kk) {
            float a[8], b[8];
            #pragma unroll
            for (int i = 0; i < 8; ++i) a[i] = As[kk][ty + 16 * i];
            #pragma unroll
            for (int j = 0; j < 8; ++j) b[j] = Ws[kk][tx + 16 * j];
            #pragma unroll
            for (int i = 0; i < 8; ++i)
                #pragma unroll
                for (int j = 0; j < 8; ++j)
                    acc[i][j] = fmaf(a[i], b[j], acc[i][j]);
        }
        __syncthreads();
    }

    #pragma unroll
    for (int i = 0; i < 8; ++i) {
        const int m = bm + ty + 16 * i;
        if (m >= M) continue;
        const float s  = dinv[m];
        const float s2 = s * s;
        #pragma unroll
        for (int j = 0; j < 8; ++j) {
            const int n = bn + tx + 16 * j;
            const float v = acc[i][j];
            Hb[(size_t)m * Nc + n]  = f2bf(v);
            Agg[(size_t)m * Nc + n] = v * s2;   // self-loop contribution
        }
    }
}

// ---------- edge-parallel gather + atomic scatter ----------
template<int DIM, int EPB>
__global__ __launch_bounds__(256) void k_edge_agg(
    const int* __restrict__ src, const int* __restrict__ dst,
    const float* __restrict__ dinv,
    const unsigned short* __restrict__ Hb,
    float* __restrict__ Agg)
{
    const int e0 = blockIdx.x * EPB;
    const int t  = threadIdx.x;
    #pragma unroll
    for (int i = 0; i < EPB; ++i) {
        const int e = e0 + i;
        const int s = src[e], d = dst[e];
        const float nrm = dinv[s] * dinv[d];
        if (DIM == 512) {
            const unsigned u = *reinterpret_cast<const unsigned*>(
                Hb + (size_t)s * DIM + 2 * t);
            const float v0 = bf2f((unsigned short)(u & 0xFFFFu)) * nrm;
            const float v1 = bf2f((unsigned short)(u >> 16)) * nrm;
            float* p = Agg + (size_t)d * DIM + 2 * t;
            atomicAdd(p,     v0);
            atomicAdd(p + 1, v1);
        } else {
            const float v = bf2f(Hb[(size_t)s * DIM + t]) * nrm;
            atomicAdd(Agg + (size_t)d * DIM + t, v);
        }
    }
}

// ---------- relu(agg + b1) -> bf16 ----------
__global__ __launch_bounds__(256) void k_relu_bias(
    const float* __restrict__ Agg, const float* __restrict__ bias,
    unsigned short* __restrict__ Out)
{
    const size_t i = (size_t)(blockIdx.x * 256 + threadIdx.x) * 4;
    const float4 v = *reinterpret_cast<const float4*>(Agg + i);
    const int d = (int)(i & (DHID - 1));
    float o0 = v.x + bias[d + 0];
    float o1 = v.y + bias[d + 1];
    float o2 = v.z + bias[d + 2];
    float o3 = v.w + bias[d + 3];
    ushort4 r;
    r.x = f2bf(o0 > 0.f ? o0 : 0.f);
    r.y = f2bf(o1 > 0.f ? o1 : 0.f);
    r.z = f2bf(o2 > 0.f ? o2 : 0.f);
    r.w = f2bf(o3 > 0.f ? o3 : 0.f);
    *reinterpret_cast<ushort4*>(Out + i) = r;
}

// ---------- log_softmax over 256 dims, one wave per node ----------
__global__ __launch_bounds__(64) void k_logsoftmax(
    float* __restrict__ O, const float* __restrict__ b2)
{
    const int node = blockIdx.x;
    const int t = threadIdx.x;
    float* row = O + (size_t)node * DOUT;
    float4 v = *reinterpret_cast<const float4*>(row + 4 * t);
    v.x += b2[4 * t + 0];
    v.y += b2[4 * t + 1];
    v.z += b2[4 * t + 2];
    v.w += b2[4 * t + 3];
    float m = fmaxf(fmaxf(v.x, v.y), fmaxf(v.z, v.w));
    #pragma unroll
    for (int off = 32; off > 0; off >>= 1) m = fmaxf(m, __shfl_xor(m, off));
    float s = expf(v.x - m) + expf(v.y - m) + expf(v.z - m) + expf(v.w - m);
    #pragma unroll
    for (int off = 32; off > 0; off >>= 1) s += __shfl_xor(s, off);
    const float lse = m + logf(s);
    v.x -= lse; v.y -= lse; v.z -= lse; v.w -= lse;
    *reinterpret_cast<float4*>(row + 4 * t) = v;
}

extern "C" void kernel_launch(void* const* d_in, const int* in_sizes, int n_in,
                              void* d_out, int out_size, void* d_ws, size_t ws_size,
                              hipStream_t stream)
{
    const float* x  = (const float*)d_in[0];
    const int*   ei = (const int*)d_in[1];
    const float* W1 = (const float*)d_in[2];
    const float* b1 = (const float*)d_in[3];
    const float* W2 = (const float*)d_in[4];
    const float* b2 = (const float*)d_in[5];
    float* out = (float*)d_out;

    const int* src = ei;        // edge_index[0]
    const int* dst = ei + NE;   // edge_index[1]

    // workspace layout (~308 MB):
    //   [0, 400KB)                       dinv (N f32)
    //   [1MB, 1MB+102.4MB)               h1 bf16 [N,512]; reused for relu(h1) bf16
    //   [1MB+102.4MB, +204.8MB)          agg1 f32 [N,512]; reused for h2 bf16 [N,256]
    char* ws = (char*)d_ws;
    float* dinv = (float*)ws;
    unsigned short* h1b = (unsigned short*)(ws + (1 << 20));
    char* ws2 = ws + (1 << 20) + (size_t)NN * DHID * 2;
    float* agg1 = (float*)ws2;
    unsigned short* h2b = (unsigned short*)ws2;

    k_init_deg <<<(NN + 255) / 256, 256, 0, stream>>>(dinv);
    k_count_deg<<<(NE + 255) / 256, 256, 0, stream>>>(dst, dinv);
    k_dinv     <<<(NN + 255) / 256, 256, 0, stream>>>(dinv);

    dim3 g1((NN + 127) / 128, DHID / 128);
    k_gemm<float><<<g1, 256, 0, stream>>>(x, W1, dinv, h1b, agg1, NN, DIN, DHID);
    k_edge_agg<DHID, 8><<<NE / 8, 256, 0, stream>>>(src, dst, dinv, h1b, agg1);
    k_relu_bias<<<NN * DHID / 4 / 256, 256, 0, stream>>>(agg1, b1, h1b);

    dim3 g2((NN + 127) / 128, DOUT / 128);
    k_gemm<unsigned short><<<g2, 256, 0, stream>>>(h1b, W2, dinv, h2b, out, NN, DHID, DOUT);
    k_edge_agg<DOUT, 8><<<NE / 8, 256, 0, stream>>>(src, dst, dinv, h2b, out);
    k_logsoftmax<<<NN, 64, 0, stream>>>(out, b2);
}

// Round 4
// 1489.914 us; speedup vs baseline: 3.0567x; 3.0567x over previous
//
#include <hip/hip_runtime.h>
#include <hip/hip_bf16.h>

#define NN   100000
#define NE   800000
#define DIN  512
#define DHID 512
#define DOUT 256
#define SCAN_B 1024
#define NSCAN ((NN + SCAN_B - 1) / SCAN_B)   // 98

__device__ __forceinline__ float bf2f(unsigned short b) {
    union { unsigned u; float f; } c; c.u = ((unsigned)b) << 16; return c.f;
}
__device__ __forceinline__ unsigned short f2bf(float f) {
    union { float f; unsigned u; } c; c.f = f;
    unsigned u = c.u;
    u += 0x7FFFu + ((u >> 16) & 1u);   // round-to-nearest-even
    return (unsigned short)(u >> 16);
}

// ---------- CSR build ----------
__global__ void k_zero2(int* a, int* b) {
    int i = blockIdx.x * 256 + threadIdx.x;
    if (i < NN) { a[i] = 0; b[i] = 0; }
}
__global__ void k_hist(const int* __restrict__ dst, int* __restrict__ cnt) {
    int i = blockIdx.x * 256 + threadIdx.x;
    if (i < NE) atomicAdd(&cnt[dst[i]], 1);
}
__global__ void k_dinv(const int* __restrict__ cnt, float* __restrict__ dinv) {
    int i = blockIdx.x * 256 + threadIdx.x;
    if (i < NN) dinv[i] = rsqrtf((float)cnt[i] + 1.0f);   // +1 self-loop
}
__global__ __launch_bounds__(SCAN_B) void k_scan1(
    const int* __restrict__ cnt, int* __restrict__ rowptr, int* __restrict__ bsums)
{
    __shared__ int sh[SCAN_B];
    const int g = blockIdx.x * SCAN_B + threadIdx.x;
    const int v = (g < NN) ? cnt[g] : 0;
    sh[threadIdx.x] = v;
    __syncthreads();
    for (int off = 1; off < SCAN_B; off <<= 1) {
        int t = (threadIdx.x >= off) ? sh[threadIdx.x - off] : 0;
        __syncthreads();
        sh[threadIdx.x] += t;
        __syncthreads();
    }
    if (g < NN) rowptr[g] = sh[threadIdx.x] - v;          // exclusive
    if (threadIdx.x == SCAN_B - 1) bsums[blockIdx.x] = sh[threadIdx.x];
}
__global__ void k_scan2(int* bsums, int* rowptr) {
    if (threadIdx.x == 0 && blockIdx.x == 0) {
        int run = 0;
        for (int i = 0; i < NSCAN; ++i) { int t = bsums[i]; bsums[i] = run; run += t; }
        rowptr[NN] = run;                                  // == NE
    }
}
__global__ __launch_bounds__(SCAN_B) void k_scan3(
    int* __restrict__ rowptr, const int* __restrict__ bsums)
{
    const int g = blockIdx.x * SCAN_B + threadIdx.x;
    if (g < NN) rowptr[g] += bsums[blockIdx.x];
}
__global__ void k_fill(const int* __restrict__ src, const int* __restrict__ dst,
                       const int* __restrict__ rowptr, int* __restrict__ cur,
                       int* __restrict__ col)
{
    int i = blockIdx.x * 256 + threadIdx.x;
    if (i < NE) {
        const int d = dst[i];
        const int slot = rowptr[d] + atomicAdd(&cur[d], 1);
        col[slot] = src[i];
    }
}

// ---------- fp32 register-tiled GEMM; epilogue writes h_scaled = h * dinv[m] (bf16) ----------
__device__ __forceinline__ void loadA4(const float* p, float* o) {
    const float4 v = *reinterpret_cast<const float4*>(p);
    o[0] = v.x; o[1] = v.y; o[2] = v.z; o[3] = v.w;
}
__device__ __forceinline__ void loadA4(const unsigned short* p, float* o) {
    const ushort4 v = *reinterpret_cast<const ushort4*>(p);
    o[0] = bf2f(v.x); o[1] = bf2f(v.y); o[2] = bf2f(v.z); o[3] = bf2f(v.w);
}

template<typename TA>
__global__ __launch_bounds__(256) void k_gemm(
    const TA* __restrict__ A, const float* __restrict__ W,
    const float* __restrict__ dinv,
    unsigned short* __restrict__ Hb,   // [M,Nc] bf16 h*dinv[m]
    int M, int K, int Nc)
{
    const int BM = 128, BN = 128, BK = 8;
    __shared__ float As[BK][BM + 4];
    __shared__ float Ws[BK][BN + 4];
    const int bm = blockIdx.x * BM;
    const int bn = blockIdx.y * BN;
    const int t  = threadIdx.x;
    const int tx = t & 15, ty = t >> 4;

    float acc[8][8];
    #pragma unroll
    for (int i = 0; i < 8; ++i)
        #pragma unroll
        for (int j = 0; j < 8; ++j) acc[i][j] = 0.f;

    const int arow = t >> 1;
    const int acol = (t & 1) * 4;
    const int wrow = t >> 5;
    const int wcol = (t & 31) * 4;

    for (int k0 = 0; k0 < K; k0 += BK) {
        float av[4] = {0.f, 0.f, 0.f, 0.f};
        const int gm = bm + arow;
        if (gm < M) loadA4(A + (size_t)gm * K + k0 + acol, av);
        As[acol + 0][arow] = av[0];
        As[acol + 1][arow] = av[1];
        As[acol + 2][arow] = av[2];
        As[acol + 3][arow] = av[3];
        const float4 wv = *reinterpret_cast<const float4*>(
            W + (size_t)(k0 + wrow) * Nc + bn + wcol);
        *reinterpret_cast<float4*>(&Ws[wrow][wcol]) = wv;
        __syncthreads();
        #pragma unroll
        for (int kk = 0; kk < BK; ++kk) {
            float a[8], b[8];
            #pragma unroll
            for (int i = 0; i < 8; ++i) a[i] = As[kk][ty + 16 * i];
            #pragma unroll
            for (int j = 0; j < 8; ++j) b[j] = Ws[kk][tx + 16 * j];
            #pragma unroll
            for (int i = 0; i < 8; ++i)
                #pragma unroll
                for (int j = 0; j < 8; ++j)
                    acc[i][j] = fmaf(a[i], b[j], acc[i][j]);
        }
        __syncthreads();
    }

    #pragma unroll
    for (int i = 0; i < 8; ++i) {
        const int m = bm + ty + 16 * i;
        if (m >= M) continue;
        const float s = dinv[m];
        #pragma unroll
        for (int j = 0; j < 8; ++j) {
            const int n = bn + tx + 16 * j;
            Hb[(size_t)m * Nc + n] = f2bf(acc[i][j] * s);
        }
    }
}

// ---------- CSR pull, D=512: one wave per node, fused bias+relu, bf16 out ----------
__device__ __forceinline__ void add8(const uint4 u, float* a) {
    a[0] += bf2f((unsigned short)(u.x));  a[1] += bf2f((unsigned short)(u.x >> 16));
    a[2] += bf2f((unsigned short)(u.y));  a[3] += bf2f((unsigned short)(u.y >> 16));
    a[4] += bf2f((unsigned short)(u.z));  a[5] += bf2f((unsigned short)(u.z >> 16));
    a[6] += bf2f((unsigned short)(u.w));  a[7] += bf2f((unsigned short)(u.w >> 16));
}

__global__ __launch_bounds__(256) void k_pull512(
    const int* __restrict__ rowptr, const int* __restrict__ col,
    const float* __restrict__ dinv, const unsigned short* __restrict__ H,
    const float* __restrict__ bias, unsigned short* __restrict__ Out)
{
    const int node = blockIdx.x * 4 + (threadIdx.x >> 6);
    if (node >= NN) return;
    const int lane = threadIdx.x & 63;

    float a[8] = {0.f, 0.f, 0.f, 0.f, 0.f, 0.f, 0.f, 0.f};
    // self-loop: own (already dinv-scaled) row
    add8(*reinterpret_cast<const uint4*>(H + (size_t)node * DHID + lane * 8), a);

    const int e0 = rowptr[node], e1 = rowptr[node + 1];
    for (int e = e0; e < e1; ++e) {
        const int s = col[e];
        add8(*reinterpret_cast<const uint4*>(H + (size_t)s * DHID + lane * 8), a);
    }

    const float sc = dinv[node];
    unsigned o[4];
    #pragma unroll
    for (int p = 0; p < 4; ++p) {
        float v0 = a[2 * p]     * sc + bias[lane * 8 + 2 * p];
        float v1 = a[2 * p + 1] * sc + bias[lane * 8 + 2 * p + 1];
        v0 = v0 > 0.f ? v0 : 0.f;
        v1 = v1 > 0.f ? v1 : 0.f;
        o[p] = (unsigned)f2bf(v0) | ((unsigned)f2bf(v1) << 16);
    }
    uint4 r = {o[0], o[1], o[2], o[3]};
    *reinterpret_cast<uint4*>(Out + (size_t)node * DHID + lane * 8) = r;
}

// ---------- CSR pull, D=256: one wave per node, fused bias+log_softmax, f32 out ----------
__device__ __forceinline__ void add4(const uint2 u, float* a) {
    a[0] += bf2f((unsigned short)(u.x));  a[1] += bf2f((unsigned short)(u.x >> 16));
    a[2] += bf2f((unsigned short)(u.y));  a[3] += bf2f((unsigned short)(u.y >> 16));
}

__global__ __launch_bounds__(256) void k_pull256_lsm(
    const int* __restrict__ rowptr, const int* __restrict__ col,
    const float* __restrict__ dinv, const unsigned short* __restrict__ H,
    const float* __restrict__ b2, float* __restrict__ out)
{
    const int node = blockIdx.x * 4 + (threadIdx.x >> 6);
    if (node >= NN) return;
    const int lane = threadIdx.x & 63;

    float a[4] = {0.f, 0.f, 0.f, 0.f};
    add4(*reinterpret_cast<const uint2*>(H + (size_t)node * DOUT + lane * 4), a);

    const int e0 = rowptr[node], e1 = rowptr[node + 1];
    for (int e = e0; e < e1; ++e) {
        const int s = col[e];
        add4(*reinterpret_cast<const uint2*>(H + (size_t)s * DOUT + lane * 4), a);
    }

    const float sc = dinv[node];
    float v0 = a[0] * sc + b2[lane * 4 + 0];
    float v1 = a[1] * sc + b2[lane * 4 + 1];
    float v2 = a[2] * sc + b2[lane * 4 + 2];
    float v3 = a[3] * sc + b2[lane * 4 + 3];

    float m = fmaxf(fmaxf(v0, v1), fmaxf(v2, v3));
    #pragma unroll
    for (int off = 32; off > 0; off >>= 1) m = fmaxf(m, __shfl_xor(m, off));
    float s = expf(v0 - m) + expf(v1 - m) + expf(v2 - m) + expf(v3 - m);
    #pragma unroll
    for (int off = 32; off > 0; off >>= 1) s += __shfl_xor(s, off);
    const float lse = m + logf(s);

    float4 r = {v0 - lse, v1 - lse, v2 - lse, v3 - lse};
    *reinterpret_cast<float4*>(out + (size_t)node * DOUT + lane * 4) = r;
}

extern "C" void kernel_launch(void* const* d_in, const int* in_sizes, int n_in,
                              void* d_out, int out_size, void* d_ws, size_t ws_size,
                              hipStream_t stream)
{
    const float* x  = (const float*)d_in[0];
    const int*   ei = (const int*)d_in[1];
    const float* W1 = (const float*)d_in[2];
    const float* b1 = (const float*)d_in[3];
    const float* W2 = (const float*)d_in[4];
    const float* b2 = (const float*)d_in[5];
    float* out = (float*)d_out;

    const int* src = ei;        // edge_index[0]
    const int* dst = ei + NE;   // edge_index[1]

    // workspace layout:
    //   0.0MB : cnt     int[NN]
    //   0.5MB : cur     int[NN]
    //   1.0MB : rowptr  int[NN+1]
    //   1.5MB : bsums   int[NSCAN]
    //   2.0MB : dinv    f32[NN]
    //   3.0MB : col     int[NE]            (3.2MB)
    //   8.0MB : H1      bf16[NN,512]       (102.4MB)  h1*dinv
    // 112.0MB : Hr      bf16[NN,512]       (102.4MB)  relu(agg1+b1)
    // 216.0MB : H2      bf16[NN,256]       (51.2MB)   h2*dinv
    char* ws = (char*)d_ws;
    int*   cnt    = (int*)(ws);
    int*   cur    = (int*)(ws + (size_t)(0.5 * (1 << 20)));
    int*   rowptr = (int*)(ws + (1 << 20));
    int*   bsums  = (int*)(ws + (size_t)(1.5 * (1 << 20)));
    float* dinv   = (float*)(ws + 2 * (1 << 20));
    int*   col    = (int*)(ws + 3 * (1 << 20));
    unsigned short* H1 = (unsigned short*)(ws + (size_t)8   * (1 << 20));
    unsigned short* Hr = (unsigned short*)(ws + (size_t)112 * (1 << 20));
    unsigned short* H2 = (unsigned short*)(ws + (size_t)216 * (1 << 20));

    const int g256n = (NN + 255) / 256;
    const int g256e = (NE + 255) / 256;

    k_zero2<<<g256n, 256, 0, stream>>>(cnt, cur);
    k_hist <<<g256e, 256, 0, stream>>>(dst, cnt);
    k_dinv <<<g256n, 256, 0, stream>>>(cnt, dinv);
    k_scan1<<<NSCAN, SCAN_B, 0, stream>>>(cnt, rowptr, bsums);
    k_scan2<<<1, 64, 0, stream>>>(bsums, rowptr);
    k_scan3<<<NSCAN, SCAN_B, 0, stream>>>(rowptr, bsums);
    k_fill <<<g256e, 256, 0, stream>>>(src, dst, rowptr, cur, col);

    dim3 g1((NN + 127) / 128, DHID / 128);
    k_gemm<float><<<g1, 256, 0, stream>>>(x, W1, dinv, H1, NN, DIN, DHID);
    k_pull512<<<(NN + 3) / 4, 256, 0, stream>>>(rowptr, col, dinv, H1, b1, Hr);

    dim3 g2((NN + 127) / 128, DOUT / 128);
    k_gemm<unsigned short><<<g2, 256, 0, stream>>>(Hr, W2, dinv, H2, NN, DHID, DOUT);
    k_pull256_lsm<<<(NN + 3) / 4, 256, 0, stream>>>(rowptr, col, dinv, H2, b2, out);
}

// Round 5
// 544.657 us; speedup vs baseline: 8.3616x; 2.7355x over previous
//
#include <hip/hip_runtime.h>
#include <hip/hip_bf16.h>

#define NN   100000
#define NE   800000
#define DIN  512
#define DHID 512
#define DOUT 256
#define SCAN_B 1024
#define NSCAN ((NN + SCAN_B - 1) / SCAN_B)   // 98

typedef short  s16x8 __attribute__((ext_vector_type(8)));
typedef float  f32x4 __attribute__((ext_vector_type(4)));

__device__ __forceinline__ float bf2f(unsigned short b) {
    union { unsigned u; float f; } c; c.u = ((unsigned)b) << 16; return c.f;
}
__device__ __forceinline__ unsigned short f2bf(float f) {
    union { float f; unsigned u; } c; c.f = f;
    unsigned u = c.u;
    u += 0x7FFFu + ((u >> 16) & 1u);   // round-to-nearest-even
    return (unsigned short)(u >> 16);
}

__device__ __forceinline__ void gload_lds16(const void* g, void* l) {
    __builtin_amdgcn_global_load_lds(
        (const __attribute__((address_space(1))) void*)g,
        (__attribute__((address_space(3))) void*)l, 16, 0, 0);
}

// ---------- CSR build ----------
__global__ void k_zero2(int* a, int* b) {
    int i = blockIdx.x * 256 + threadIdx.x;
    if (i < NN) { a[i] = 0; b[i] = 0; }
}
__global__ void k_hist(const int* __restrict__ dst, int* __restrict__ cnt) {
    int i = blockIdx.x * 256 + threadIdx.x;
    if (i < NE) atomicAdd(&cnt[dst[i]], 1);
}
__global__ void k_dinv(const int* __restrict__ cnt, float* __restrict__ dinv) {
    int i = blockIdx.x * 256 + threadIdx.x;
    if (i < NN) dinv[i] = rsqrtf((float)cnt[i] + 1.0f);   // +1 self-loop
}
__global__ __launch_bounds__(SCAN_B) void k_scan1(
    const int* __restrict__ cnt, int* __restrict__ rowptr, int* __restrict__ bsums)
{
    __shared__ int sh[SCAN_B];
    const int g = blockIdx.x * SCAN_B + threadIdx.x;
    const int v = (g < NN) ? cnt[g] : 0;
    sh[threadIdx.x] = v;
    __syncthreads();
    for (int off = 1; off < SCAN_B; off <<= 1) {
        int t = (threadIdx.x >= off) ? sh[threadIdx.x - off] : 0;
        __syncthreads();
        sh[threadIdx.x] += t;
        __syncthreads();
    }
    if (g < NN) rowptr[g] = sh[threadIdx.x] - v;          // exclusive
    if (threadIdx.x == SCAN_B - 1) bsums[blockIdx.x] = sh[threadIdx.x];
}
__global__ void k_scan2(int* bsums, int* rowptr) {
    if (threadIdx.x == 0 && blockIdx.x == 0) {
        int run = 0;
        for (int i = 0; i < NSCAN; ++i) { int t = bsums[i]; bsums[i] = run; run += t; }
        rowptr[NN] = run;                                  // == NE
    }
}
__global__ __launch_bounds__(SCAN_B) void k_scan3(
    int* __restrict__ rowptr, const int* __restrict__ bsums)
{
    const int g = blockIdx.x * SCAN_B + threadIdx.x;
    if (g < NN) rowptr[g] += bsums[blockIdx.x];
}
__global__ void k_fill(const int* __restrict__ src, const int* __restrict__ dst,
                       const int* __restrict__ rowptr, int* __restrict__ cur,
                       int* __restrict__ col)
{
    int i = blockIdx.x * 256 + threadIdx.x;
    if (i < NE) {
        const int d = dst[i];
        const int slot = rowptr[d] + atomicAdd(&cur[d], 1);
        col[slot] = src[i];
    }
}

// ---------- dtype prep ----------
__global__ __launch_bounds__(256) void k_x2bf(const float* __restrict__ x,
                                              unsigned short* __restrict__ xb)
{
    const size_t i = (size_t)(blockIdx.x * 256 + threadIdx.x) * 8;
    if (i >= (size_t)NN * DIN) return;
    const float4 v0 = *reinterpret_cast<const float4*>(x + i);
    const float4 v1 = *reinterpret_cast<const float4*>(x + i + 4);
    uint4 r;
    r.x = (unsigned)f2bf(v0.x) | ((unsigned)f2bf(v0.y) << 16);
    r.y = (unsigned)f2bf(v0.z) | ((unsigned)f2bf(v0.w) << 16);
    r.z = (unsigned)f2bf(v1.x) | ((unsigned)f2bf(v1.y) << 16);
    r.w = (unsigned)f2bf(v1.z) | ((unsigned)f2bf(v1.w) << 16);
    *reinterpret_cast<uint4*>(xb + i) = r;
}

// W[512][NCOLS] f32 -> Wt[NCOLS][512] bf16
template<int NCOLS>
__global__ __launch_bounds__(256) void k_wt(const float* __restrict__ W,
                                            unsigned short* __restrict__ Wt)
{
    const int idx = blockIdx.x * 256 + threadIdx.x;
    if (idx >= 512 * NCOLS) return;
    const int k = idx / NCOLS, n = idx % NCOLS;
    Wt[n * 512 + k] = f2bf(W[idx]);
}

// ---------- bf16 MFMA GEMM: C[M][NC] = A[M][512] x Wt[NC][512]^T ----------
// 128x128 tile, 4 waves (2x2), each wave 64x64 = 4x4 frags of 16x16, BK=32.
// LDS chunk-swizzle: slot (row, cp) holds logical chunk cp ^ ((row>>1)&3)
// (applied on the global SOURCE at staging and on the ds_read address; 2-way
//  bank aliasing = free).  Epilogue: *dinv[m], bf16 store.
template<int NC>
__global__ __launch_bounds__(256) void k_mfma_gemm(
    const unsigned short* __restrict__ A,   // [M][512] bf16
    const unsigned short* __restrict__ Wt,  // [NC][512] bf16
    const float* __restrict__ dinv,
    unsigned short* __restrict__ Hb,        // [M][NC] bf16  (h*dinv[m])
    int M)
{
    constexpr int K = 512;
    __shared__ __align__(16) unsigned short As[128 * 32];
    __shared__ __align__(16) unsigned short Bs[128 * 32];

    const int bm = blockIdx.x * 128;
    const int bn = blockIdx.y * 128;
    const int t    = threadIdx.x;
    const int lane = t & 63;
    const int wid  = t >> 6;
    const int wr = wid >> 1, wc = wid & 1;

    f32x4 acc[4][4];
    #pragma unroll
    for (int i = 0; i < 4; ++i)
        #pragma unroll
        for (int j = 0; j < 4; ++j)
            acc[i][j] = (f32x4){0.f, 0.f, 0.f, 0.f};

    const int r16 = lane & 15;
    const int kc  = lane >> 4;               // 0..3 (k-chunk of 8)

    for (int k0 = 0; k0 < K; k0 += 32) {
        // ---- stage A-tile [128][32] and B-tile [128][32] (8KB each) ----
        #pragma unroll
        for (int i = 0; i < 2; ++i) {
            const int c   = i * 256 + t;     // 16B chunk index, 0..511
            const int row = c >> 2;
            const int cp  = c & 3;
            const int sc  = cp ^ ((row >> 1) & 3);   // pre-permuted source chunk
            const int gr  = (bm + row < M) ? bm + row : M - 1;
            gload_lds16(A  + (size_t)gr * K + k0 + sc * 8,
                        &As[(size_t)(i * 256 + wid * 64) * 8]);
            gload_lds16(Wt + (size_t)(bn + row) * K + k0 + sc * 8,
                        &Bs[(size_t)(i * 256 + wid * 64) * 8]);
        }
        __syncthreads();

        // ---- fragments + 16 MFMA ----
        s16x8 af[4], bf[4];
        #pragma unroll
        for (int i = 0; i < 4; ++i) {
            const int ra = wr * 64 + i * 16 + r16;
            af[i] = *reinterpret_cast<const s16x8*>(
                &As[ra * 32 + ((kc ^ ((ra >> 1) & 3)) * 8)]);
            const int rb = wc * 64 + i * 16 + r16;
            bf[i] = *reinterpret_cast<const s16x8*>(
                &Bs[rb * 32 + ((kc ^ ((rb >> 1) & 3)) * 8)]);
        }
        #pragma unroll
        for (int i = 0; i < 4; ++i)
            #pragma unroll
            for (int j = 0; j < 4; ++j)
                acc[i][j] = __builtin_amdgcn_mfma_f32_16x16x32_bf16(
                    af[i], bf[j], acc[i][j], 0, 0, 0);
        __syncthreads();
    }

    // ---- epilogue: C[row=(lane>>4)*4+r][col=lane&15] per frag ----
    #pragma unroll
    for (int i = 0; i < 4; ++i) {
        #pragma unroll
        for (int r = 0; r < 4; ++r) {
            const int m = bm + wr * 64 + i * 16 + (lane >> 4) * 4 + r;
            if (m >= M) continue;
            const float s = dinv[m];
            #pragma unroll
            for (int j = 0; j < 4; ++j) {
                const int n = bn + wc * 64 + j * 16 + (lane & 15);
                Hb[(size_t)m * NC + n] = f2bf(acc[i][j][r] * s);
            }
        }
    }
}

// ---------- CSR pull, D=512: one wave per node, fused bias+relu, bf16 out ----------
__device__ __forceinline__ void add8(const uint4 u, float* a) {
    a[0] += bf2f((unsigned short)(u.x));  a[1] += bf2f((unsigned short)(u.x >> 16));
    a[2] += bf2f((unsigned short)(u.y));  a[3] += bf2f((unsigned short)(u.y >> 16));
    a[4] += bf2f((unsigned short)(u.z));  a[5] += bf2f((unsigned short)(u.z >> 16));
    a[6] += bf2f((unsigned short)(u.w));  a[7] += bf2f((unsigned short)(u.w >> 16));
}

__global__ __launch_bounds__(256) void k_pull512(
    const int* __restrict__ rowptr, const int* __restrict__ col,
    const float* __restrict__ dinv, const unsigned short* __restrict__ H,
    const float* __restrict__ bias, unsigned short* __restrict__ Out)
{
    const int node = blockIdx.x * 4 + (threadIdx.x >> 6);
    if (node >= NN) return;
    const int lane = threadIdx.x & 63;

    float a[8] = {0.f, 0.f, 0.f, 0.f, 0.f, 0.f, 0.f, 0.f};
    add8(*reinterpret_cast<const uint4*>(H + (size_t)node * DHID + lane * 8), a);

    const int e0 = rowptr[node], e1 = rowptr[node + 1];
    for (int e = e0; e < e1; ++e) {
        const int s = col[e];
        add8(*reinterpret_cast<const uint4*>(H + (size_t)s * DHID + lane * 8), a);
    }

    const float sc = dinv[node];
    unsigned o[4];
    #pragma unroll
    for (int p = 0; p < 4; ++p) {
        float v0 = a[2 * p]     * sc + bias[lane * 8 + 2 * p];
        float v1 = a[2 * p + 1] * sc + bias[lane * 8 + 2 * p + 1];
        v0 = v0 > 0.f ? v0 : 0.f;
        v1 = v1 > 0.f ? v1 : 0.f;
        o[p] = (unsigned)f2bf(v0) | ((unsigned)f2bf(v1) << 16);
    }
    uint4 r = {o[0], o[1], o[2], o[3]};
    *reinterpret_cast<uint4*>(Out + (size_t)node * DHID + lane * 8) = r;
}

// ---------- CSR pull, D=256: fused bias+log_softmax, f32 out ----------
__device__ __forceinline__ void add4(const uint2 u, float* a) {
    a[0] += bf2f((unsigned short)(u.x));  a[1] += bf2f((unsigned short)(u.x >> 16));
    a[2] += bf2f((unsigned short)(u.y));  a[3] += bf2f((unsigned short)(u.y >> 16));
}

__global__ __launch_bounds__(256) void k_pull256_lsm(
    const int* __restrict__ rowptr, const int* __restrict__ col,
    const float* __restrict__ dinv, const unsigned short* __restrict__ H,
    const float* __restrict__ b2, float* __restrict__ out)
{
    const int node = blockIdx.x * 4 + (threadIdx.x >> 6);
    if (node >= NN) return;
    const int lane = threadIdx.x & 63;

    float a[4] = {0.f, 0.f, 0.f, 0.f};
    add4(*reinterpret_cast<const uint2*>(H + (size_t)node * DOUT + lane * 4), a);

    const int e0 = rowptr[node], e1 = rowptr[node + 1];
    for (int e = e0; e < e1; ++e) {
        const int s = col[e];
        add4(*reinterpret_cast<const uint2*>(H + (size_t)s * DOUT + lane * 4), a);
    }

    const float sc = dinv[node];
    float v0 = a[0] * sc + b2[lane * 4 + 0];
    float v1 = a[1] * sc + b2[lane * 4 + 1];
    float v2 = a[2] * sc + b2[lane * 4 + 2];
    float v3 = a[3] * sc + b2[lane * 4 + 3];

    float m = fmaxf(fmaxf(v0, v1), fmaxf(v2, v3));
    #pragma unroll
    for (int off = 32; off > 0; off >>= 1) m = fmaxf(m, __shfl_xor(m, off));
    float s = expf(v0 - m) + expf(v1 - m) + expf(v2 - m) + expf(v3 - m);
    #pragma unroll
    for (int off = 32; off > 0; off >>= 1) s += __shfl_xor(s, off);
    const float lse = m + logf(s);

    float4 r = {v0 - lse, v1 - lse, v2 - lse, v3 - lse};
    *reinterpret_cast<float4*>(out + (size_t)node * DOUT + lane * 4) = r;
}

extern "C" void kernel_launch(void* const* d_in, const int* in_sizes, int n_in,
                              void* d_out, int out_size, void* d_ws, size_t ws_size,
                              hipStream_t stream)
{
    const float* x  = (const float*)d_in[0];
    const int*   ei = (const int*)d_in[1];
    const float* W1 = (const float*)d_in[2];
    const float* b1 = (const float*)d_in[3];
    const float* W2 = (const float*)d_in[4];
    const float* b2 = (const float*)d_in[5];
    float* out = (float*)d_out;

    const int* src = ei;        // edge_index[0]
    const int* dst = ei + NE;   // edge_index[1]

    // workspace (high-water ~210 MiB):
    //   0.0MB cnt | 0.5 cur | 1.0 rowptr | 1.5 bsums | 2.0 dinv | 3.0 col
    //   6.5MB Wt1 bf16[512][512] | 7.0MB Wt2 bf16[256][512]
    //   8MiB   P: xb bf16[NN][512]  -> reused as Hr bf16[NN][512]
    //   112MiB Q: H1 bf16[NN][512]  -> reused as H2 bf16[NN][256]
    char* ws = (char*)d_ws;
    int*   cnt    = (int*)(ws);
    int*   cur    = (int*)(ws + (size_t)(1 << 19));
    int*   rowptr = (int*)(ws + (size_t)(1 << 20));
    int*   bsums  = (int*)(ws + (size_t)(3 << 19));
    float* dinv   = (float*)(ws + (size_t)(2 << 20));
    int*   col    = (int*)(ws + (size_t)(3 << 20));
    unsigned short* Wt1 = (unsigned short*)(ws + (size_t)(13 << 19));     // 6.5MiB
    unsigned short* Wt2 = (unsigned short*)(ws + (size_t)(7 << 20));      // 7.0MiB
    unsigned short* P   = (unsigned short*)(ws + (size_t)8   * (1 << 20));
    unsigned short* Q   = (unsigned short*)(ws + (size_t)112 * (1 << 20));
    unsigned short* xb = P, * Hr = P;
    unsigned short* H1 = Q, * H2 = Q;

    const int g256n = (NN + 255) / 256;
    const int g256e = (NE + 255) / 256;

    k_zero2<<<g256n, 256, 0, stream>>>(cnt, cur);
    k_hist <<<g256e, 256, 0, stream>>>(dst, cnt);
    k_dinv <<<g256n, 256, 0, stream>>>(cnt, dinv);
    k_scan1<<<NSCAN, SCAN_B, 0, stream>>>(cnt, rowptr, bsums);
    k_scan2<<<1, 64, 0, stream>>>(bsums, rowptr);
    k_scan3<<<NSCAN, SCAN_B, 0, stream>>>(rowptr, bsums);
    k_fill <<<g256e, 256, 0, stream>>>(src, dst, rowptr, cur, col);

    k_x2bf<<<(int)(((size_t)NN * DIN / 8 + 255) / 256), 256, 0, stream>>>(x, xb);
    k_wt<512><<<(512 * 512 + 255) / 256, 256, 0, stream>>>(W1, Wt1);
    k_wt<256><<<(512 * 256 + 255) / 256, 256, 0, stream>>>(W2, Wt2);

    dim3 g1((NN + 127) / 128, DHID / 128);
    k_mfma_gemm<DHID><<<g1, 256, 0, stream>>>(xb, Wt1, dinv, H1, NN);
    k_pull512<<<(NN + 3) / 4, 256, 0, stream>>>(rowptr, col, dinv, H1, b1, Hr);

    dim3 g2((NN + 127) / 128, DOUT / 128);
    k_mfma_gemm<DOUT><<<g2, 256, 0, stream>>>(Hr, Wt2, dinv, H2, NN);
    k_pull256_lsm<<<(NN + 3) / 4, 256, 0, stream>>>(rowptr, col, dinv, H2, b2, out);
}

// Round 6
// 509.259 us; speedup vs baseline: 8.9429x; 1.0695x over previous
//
#include <hip/hip_runtime.h>
#include <hip/hip_bf16.h>

#define NN   100000
#define NE   800000
#define DIN  512
#define DHID 512
#define DOUT 256
#define SCAN_B 1024
#define NSCAN ((NN + SCAN_B - 1) / SCAN_B)   // 98

typedef short  s16x8 __attribute__((ext_vector_type(8)));
typedef float  f32x4 __attribute__((ext_vector_type(4)));

__device__ __forceinline__ float bf2f(unsigned short b) {
    union { unsigned u; float f; } c; c.u = ((unsigned)b) << 16; return c.f;
}
__device__ __forceinline__ unsigned short f2bf(float f) {
    union { float f; unsigned u; } c; c.f = f;
    unsigned u = c.u;
    u += 0x7FFFu + ((u >> 16) & 1u);   // round-to-nearest-even
    return (unsigned short)(u >> 16);
}

__device__ __forceinline__ void gload_lds16(const void* g, void* l) {
    __builtin_amdgcn_global_load_lds(
        (const __attribute__((address_space(1))) void*)g,
        (__attribute__((address_space(3))) void*)l, 16, 0, 0);
}

// ---------- CSR build ----------
__global__ void k_zero2(int* a, int* b) {
    int i = blockIdx.x * 256 + threadIdx.x;
    if (i < NN) { a[i] = 0; b[i] = 0; }
}
__global__ void k_hist(const int* __restrict__ dst, int* __restrict__ cnt) {
    int i = blockIdx.x * 256 + threadIdx.x;
    if (i < NE) atomicAdd(&cnt[dst[i]], 1);
}
__global__ void k_dinv(const int* __restrict__ cnt, float* __restrict__ dinv) {
    int i = blockIdx.x * 256 + threadIdx.x;
    if (i < NN) dinv[i] = rsqrtf((float)cnt[i] + 1.0f);   // +1 self-loop
}
__global__ __launch_bounds__(SCAN_B) void k_scan1(
    const int* __restrict__ cnt, int* __restrict__ rowptr, int* __restrict__ bsums)
{
    __shared__ int sh[SCAN_B];
    const int g = blockIdx.x * SCAN_B + threadIdx.x;
    const int v = (g < NN) ? cnt[g] : 0;
    sh[threadIdx.x] = v;
    __syncthreads();
    for (int off = 1; off < SCAN_B; off <<= 1) {
        int t = (threadIdx.x >= off) ? sh[threadIdx.x - off] : 0;
        __syncthreads();
        sh[threadIdx.x] += t;
        __syncthreads();
    }
    if (g < NN) rowptr[g] = sh[threadIdx.x] - v;          // exclusive
    if (threadIdx.x == SCAN_B - 1) bsums[blockIdx.x] = sh[threadIdx.x];
}
__global__ void k_scan2(int* bsums, int* rowptr) {
    if (threadIdx.x == 0 && blockIdx.x == 0) {
        int run = 0;
        for (int i = 0; i < NSCAN; ++i) { int t = bsums[i]; bsums[i] = run; run += t; }
        rowptr[NN] = run;                                  // == NE
    }
}
__global__ __launch_bounds__(SCAN_B) void k_scan3(
    int* __restrict__ rowptr, const int* __restrict__ bsums)
{
    const int g = blockIdx.x * SCAN_B + threadIdx.x;
    if (g < NN) rowptr[g] += bsums[blockIdx.x];
}
__global__ void k_fill(const int* __restrict__ src, const int* __restrict__ dst,
                       const int* __restrict__ rowptr, int* __restrict__ cur,
                       int* __restrict__ col)
{
    int i = blockIdx.x * 256 + threadIdx.x;
    if (i < NE) {
        const int d = dst[i];
        const int slot = rowptr[d] + atomicAdd(&cur[d], 1);
        col[slot] = src[i];
    }
}

// ---------- dtype prep ----------
__global__ __launch_bounds__(256) void k_x2bf(const float* __restrict__ x,
                                              unsigned short* __restrict__ xb)
{
    const size_t i = (size_t)(blockIdx.x * 256 + threadIdx.x) * 8;
    if (i >= (size_t)NN * DIN) return;
    const float4 v0 = *reinterpret_cast<const float4*>(x + i);
    const float4 v1 = *reinterpret_cast<const float4*>(x + i + 4);
    uint4 r;
    r.x = (unsigned)f2bf(v0.x) | ((unsigned)f2bf(v0.y) << 16);
    r.y = (unsigned)f2bf(v0.z) | ((unsigned)f2bf(v0.w) << 16);
    r.z = (unsigned)f2bf(v1.x) | ((unsigned)f2bf(v1.y) << 16);
    r.w = (unsigned)f2bf(v1.z) | ((unsigned)f2bf(v1.w) << 16);
    *reinterpret_cast<uint4*>(xb + i) = r;
}

// W[512][NCOLS] f32 -> Wt[NCOLS][512] bf16
template<int NCOLS>
__global__ __launch_bounds__(256) void k_wt(const float* __restrict__ W,
                                            unsigned short* __restrict__ Wt)
{
    const int idx = blockIdx.x * 256 + threadIdx.x;
    if (idx >= 512 * NCOLS) return;
    const int k = idx / NCOLS, n = idx % NCOLS;
    Wt[n * 512 + k] = f2bf(W[idx]);
}

// ---------- bf16 MFMA GEMM: C[M][NC] = A[M][512] x Wt[NC][512]^T ----------
// 128x128 tile, 4 waves (2x2), BK=32; global_load_lds staging with chunk
// XOR-swizzle (pre-permuted global source + same XOR on ds_read).
// 1D grid, bn-fastest, XCD-bijective chunking (m204) so consecutive blocks
// on one XCD share the A-panel in its private L2.
template<int NC>
__global__ __launch_bounds__(256) void k_mfma_gemm(
    const unsigned short* __restrict__ A,   // [M][512] bf16
    const unsigned short* __restrict__ Wt,  // [NC][512] bf16
    const float* __restrict__ dinv,
    unsigned short* __restrict__ Hb,        // [M][NC] bf16  (h*dinv[m])
    int M)
{
    constexpr int K  = 512;
    constexpr int GN = NC / 128;
    __shared__ __align__(16) unsigned short As[128 * 32];
    __shared__ __align__(16) unsigned short Bs[128 * 32];

    const int GM  = (M + 127) >> 7;
    const int nwg = GM * GN;
    const int bid = blockIdx.x;
    const int q = nwg >> 3, r = nwg & 7;
    const int xcd = bid & 7, pos = bid >> 3;
    const int sbid = (xcd < r ? xcd * (q + 1) : r * (q + 1) + (xcd - r) * q) + pos;
    const int bm = (sbid / GN) * 128;
    const int bn = (sbid % GN) * 128;

    const int t    = threadIdx.x;
    const int lane = t & 63;
    const int wid  = t >> 6;
    const int wr = wid >> 1, wc = wid & 1;

    f32x4 acc[4][4];
    #pragma unroll
    for (int i = 0; i < 4; ++i)
        #pragma unroll
        for (int j = 0; j < 4; ++j)
            acc[i][j] = (f32x4){0.f, 0.f, 0.f, 0.f};

    const int r16 = lane & 15;
    const int kc  = lane >> 4;               // 0..3 (k-chunk of 8)

    for (int k0 = 0; k0 < K; k0 += 32) {
        #pragma unroll
        for (int i = 0; i < 2; ++i) {
            const int c   = i * 256 + t;     // 16B chunk index, 0..511
            const int row = c >> 2;
            const int cp  = c & 3;
            const int sc  = cp ^ ((row >> 1) & 3);   // pre-permuted source chunk
            const int gr  = (bm + row < M) ? bm + row : M - 1;
            gload_lds16(A  + (size_t)gr * K + k0 + sc * 8,
                        &As[(size_t)(i * 256 + wid * 64) * 8]);
            gload_lds16(Wt + (size_t)(bn + row) * K + k0 + sc * 8,
                        &Bs[(size_t)(i * 256 + wid * 64) * 8]);
        }
        __syncthreads();

        s16x8 af[4], bf[4];
        #pragma unroll
        for (int i = 0; i < 4; ++i) {
            const int ra = wr * 64 + i * 16 + r16;
            af[i] = *reinterpret_cast<const s16x8*>(
                &As[ra * 32 + ((kc ^ ((ra >> 1) & 3)) * 8)]);
            const int rb = wc * 64 + i * 16 + r16;
            bf[i] = *reinterpret_cast<const s16x8*>(
                &Bs[rb * 32 + ((kc ^ ((rb >> 1) & 3)) * 8)]);
        }
        #pragma unroll
        for (int i = 0; i < 4; ++i)
            #pragma unroll
            for (int j = 0; j < 4; ++j)
                acc[i][j] = __builtin_amdgcn_mfma_f32_16x16x32_bf16(
                    af[i], bf[j], acc[i][j], 0, 0, 0);
        __syncthreads();
    }

    #pragma unroll
    for (int i = 0; i < 4; ++i) {
        #pragma unroll
        for (int r2 = 0; r2 < 4; ++r2) {
            const int m = bm + wr * 64 + i * 16 + (lane >> 4) * 4 + r2;
            if (m >= M) continue;
            const float s = dinv[m];
            #pragma unroll
            for (int j = 0; j < 4; ++j) {
                const int n = bn + wc * 64 + j * 16 + (lane & 15);
                Hb[(size_t)m * NC + n] = f2bf(acc[i][j][r2] * s);
            }
        }
    }
}

// ---------- CSR pull, D=512: one wave per node, batched gathers (MLP=4) ----------
__device__ __forceinline__ void add8(const uint4 u, float* a) {
    a[0] += bf2f((unsigned short)(u.x));  a[1] += bf2f((unsigned short)(u.x >> 16));
    a[2] += bf2f((unsigned short)(u.y));  a[3] += bf2f((unsigned short)(u.y >> 16));
    a[4] += bf2f((unsigned short)(u.z));  a[5] += bf2f((unsigned short)(u.z >> 16));
    a[6] += bf2f((unsigned short)(u.w));  a[7] += bf2f((unsigned short)(u.w >> 16));
}

__global__ __launch_bounds__(256) void k_pull512(
    const int* __restrict__ rowptr, const int* __restrict__ col,
    const float* __restrict__ dinv, const unsigned short* __restrict__ H,
    const float* __restrict__ bias, unsigned short* __restrict__ Out)
{
    const int node = blockIdx.x * 4 + (threadIdx.x >> 6);
    if (node >= NN) return;
    const int lane = threadIdx.x & 63;

    const int e0  = rowptr[node];
    const int deg = rowptr[node + 1] - e0;
    const int myc = (lane < deg) ? col[e0 + lane] : 0;   // wave-wide col prefetch

    float a[8] = {0.f, 0.f, 0.f, 0.f, 0.f, 0.f, 0.f, 0.f};
    add8(*reinterpret_cast<const uint4*>(H + (size_t)node * DHID + lane * 8), a);

    const int dmax = deg < 64 ? deg : 64;
    int e = 0;
    for (; e + 4 <= dmax; e += 4) {
        const int s0 = __shfl(myc, e + 0), s1 = __shfl(myc, e + 1);
        const int s2 = __shfl(myc, e + 2), s3 = __shfl(myc, e + 3);
        const uint4 r0 = *reinterpret_cast<const uint4*>(H + (size_t)s0 * DHID + lane * 8);
        const uint4 r1 = *reinterpret_cast<const uint4*>(H + (size_t)s1 * DHID + lane * 8);
        const uint4 r2 = *reinterpret_cast<const uint4*>(H + (size_t)s2 * DHID + lane * 8);
        const uint4 r3 = *reinterpret_cast<const uint4*>(H + (size_t)s3 * DHID + lane * 8);
        add8(r0, a); add8(r1, a); add8(r2, a); add8(r3, a);
    }
    for (; e < deg; ++e) {
        const int s = (e < 64) ? __shfl(myc, e) : col[e0 + e];
        add8(*reinterpret_cast<const uint4*>(H + (size_t)s * DHID + lane * 8), a);
    }

    const float sc = dinv[node];
    unsigned o[4];
    #pragma unroll
    for (int p = 0; p < 4; ++p) {
        float v0 = a[2 * p]     * sc + bias[lane * 8 + 2 * p];
        float v1 = a[2 * p + 1] * sc + bias[lane * 8 + 2 * p + 1];
        v0 = v0 > 0.f ? v0 : 0.f;
        v1 = v1 > 0.f ? v1 : 0.f;
        o[p] = (unsigned)f2bf(v0) | ((unsigned)f2bf(v1) << 16);
    }
    uint4 r = {o[0], o[1], o[2], o[3]};
    *reinterpret_cast<uint4*>(Out + (size_t)node * DHID + lane * 8) = r;
}

// ---------- CSR pull, D=256: batched gathers + fused bias+log_softmax ----------
__device__ __forceinline__ void add4(const uint2 u, float* a) {
    a[0] += bf2f((unsigned short)(u.x));  a[1] += bf2f((unsigned short)(u.x >> 16));
    a[2] += bf2f((unsigned short)(u.y));  a[3] += bf2f((unsigned short)(u.y >> 16));
}

__global__ __launch_bounds__(256) void k_pull256_lsm(
    const int* __restrict__ rowptr, const int* __restrict__ col,
    const float* __restrict__ dinv, const unsigned short* __restrict__ H,
    const float* __restrict__ b2, float* __restrict__ out)
{
    const int node = blockIdx.x * 4 + (threadIdx.x >> 6);
    if (node >= NN) return;
    const int lane = threadIdx.x & 63;

    const int e0  = rowptr[node];
    const int deg = rowptr[node + 1] - e0;
    const int myc = (lane < deg) ? col[e0 + lane] : 0;

    float a[4] = {0.f, 0.f, 0.f, 0.f};
    add4(*reinterpret_cast<const uint2*>(H + (size_t)node * DOUT + lane * 4), a);

    const int dmax = deg < 64 ? deg : 64;
    int e = 0;
    for (; e + 4 <= dmax; e += 4) {
        const int s0 = __shfl(myc, e + 0), s1 = __shfl(myc, e + 1);
        const int s2 = __shfl(myc, e + 2), s3 = __shfl(myc, e + 3);
        const uint2 r0 = *reinterpret_cast<const uint2*>(H + (size_t)s0 * DOUT + lane * 4);
        const uint2 r1 = *reinterpret_cast<const uint2*>(H + (size_t)s1 * DOUT + lane * 4);
        const uint2 r2 = *reinterpret_cast<const uint2*>(H + (size_t)s2 * DOUT + lane * 4);
        const uint2 r3 = *reinterpret_cast<const uint2*>(H + (size_t)s3 * DOUT + lane * 4);
        add4(r0, a); add4(r1, a); add4(r2, a); add4(r3, a);
    }
    for (; e < deg; ++e) {
        const int s = (e < 64) ? __shfl(myc, e) : col[e0 + e];
        add4(*reinterpret_cast<const uint2*>(H + (size_t)s * DOUT + lane * 4), a);
    }

    const float sc = dinv[node];
    float v0 = a[0] * sc + b2[lane * 4 + 0];
    float v1 = a[1] * sc + b2[lane * 4 + 1];
    float v2 = a[2] * sc + b2[lane * 4 + 2];
    float v3 = a[3] * sc + b2[lane * 4 + 3];

    float m = fmaxf(fmaxf(v0, v1), fmaxf(v2, v3));
    #pragma unroll
    for (int off = 32; off > 0; off >>= 1) m = fmaxf(m, __shfl_xor(m, off));
    float s = expf(v0 - m) + expf(v1 - m) + expf(v2 - m) + expf(v3 - m);
    #pragma unroll
    for (int off = 32; off > 0; off >>= 1) s += __shfl_xor(s, off);
    const float lse = m + logf(s);

    float4 rr = {v0 - lse, v1 - lse, v2 - lse, v3 - lse};
    *reinterpret_cast<float4*>(out + (size_t)node * DOUT + lane * 4) = rr;
}

extern "C" void kernel_launch(void* const* d_in, const int* in_sizes, int n_in,
                              void* d_out, int out_size, void* d_ws, size_t ws_size,
                              hipStream_t stream)
{
    const float* x  = (const float*)d_in[0];
    const int*   ei = (const int*)d_in[1];
    const float* W1 = (const float*)d_in[2];
    const float* b1 = (const float*)d_in[3];
    const float* W2 = (const float*)d_in[4];
    const float* b2 = (const float*)d_in[5];
    float* out = (float*)d_out;

    const int* src = ei;        // edge_index[0]
    const int* dst = ei + NE;   // edge_index[1]

    // workspace (high-water ~210 MiB):
    //   0.0MB cnt | 0.5 cur | 1.0 rowptr | 1.5 bsums | 2.0 dinv | 3.0 col
    //   6.5MB Wt1 bf16[512][512] | 7.0MB Wt2 bf16[256][512]
    //   8MiB   P: xb bf16[NN][512]  -> reused as Hr bf16[NN][512]
    //   112MiB Q: H1 bf16[NN][512]  -> reused as H2 bf16[NN][256]
    char* ws = (char*)d_ws;
    int*   cnt    = (int*)(ws);
    int*   cur    = (int*)(ws + (size_t)(1 << 19));
    int*   rowptr = (int*)(ws + (size_t)(1 << 20));
    int*   bsums  = (int*)(ws + (size_t)(3 << 19));
    float* dinv   = (float*)(ws + (size_t)(2 << 20));
    int*   col    = (int*)(ws + (size_t)(3 << 20));
    unsigned short* Wt1 = (unsigned short*)(ws + (size_t)(13 << 19));     // 6.5MiB
    unsigned short* Wt2 = (unsigned short*)(ws + (size_t)(7 << 20));      // 7.0MiB
    unsigned short* P   = (unsigned short*)(ws + (size_t)8   * (1 << 20));
    unsigned short* Q   = (unsigned short*)(ws + (size_t)112 * (1 << 20));
    unsigned short* xb = P, * Hr = P;
    unsigned short* H1 = Q, * H2 = Q;

    const int g256n = (NN + 255) / 256;
    const int g256e = (NE + 255) / 256;

    k_zero2<<<g256n, 256, 0, stream>>>(cnt, cur);
    k_hist <<<g256e, 256, 0, stream>>>(dst, cnt);
    k_dinv <<<g256n, 256, 0, stream>>>(cnt, dinv);
    k_scan1<<<NSCAN, SCAN_B, 0, stream>>>(cnt, rowptr, bsums);
    k_scan2<<<1, 64, 0, stream>>>(bsums, rowptr);
    k_scan3<<<NSCAN, SCAN_B, 0, stream>>>(rowptr, bsums);
    k_fill <<<g256e, 256, 0, stream>>>(src, dst, rowptr, cur, col);

    k_x2bf<<<(int)(((size_t)NN * DIN / 8 + 255) / 256), 256, 0, stream>>>(x, xb);
    k_wt<512><<<(512 * 512 + 255) / 256, 256, 0, stream>>>(W1, Wt1);
    k_wt<256><<<(512 * 256 + 255) / 256, 256, 0, stream>>>(W2, Wt2);

    const int GM = (NN + 127) / 128;                 // 782
    k_mfma_gemm<DHID><<<GM * (DHID / 128), 256, 0, stream>>>(xb, Wt1, dinv, H1, NN);
    k_pull512<<<(NN + 3) / 4, 256, 0, stream>>>(rowptr, col, dinv, H1, b1, Hr);

    k_mfma_gemm<DOUT><<<GM * (DOUT / 128), 256, 0, stream>>>(Hr, Wt2, dinv, H2, NN);
    k_pull256_lsm<<<(NN + 3) / 4, 256, 0, stream>>>(rowptr, col, dinv, H2, b2, out);
}